// Round 1
// baseline (4119.029 us; speedup 1.0000x reference)
//
#include <hip/hip_runtime.h>
#include <math.h>

#define B 256
#define N 128
#define E 2048
#define D 512
#define R 1024
#define O 10
#define L 5
#define K1 (D + 1)  // 513

// ---------------------------------------------------------------------------
// Zero a float buffer
// ---------------------------------------------------------------------------
__global__ void zero_kernel(float* __restrict__ p, size_t n) {
    size_t i = (size_t)blockIdx.x * blockDim.x + threadIdx.x;
    size_t stride = (size_t)gridDim.x * blockDim.x;
    for (; i < n; i += stride) p[i] = 0.f;
}

// ---------------------------------------------------------------------------
// Build per-batch adjacency count matrix C[b][dst][src] += 1
// ---------------------------------------------------------------------------
__global__ void fill_adj_kernel(const int* __restrict__ edges, float* __restrict__ C) {
    int idx = blockIdx.x * blockDim.x + threadIdx.x;
    if (idx >= B * E) return;
    int b = idx / E;
    int e = idx - b * E;
    int src = edges[b * 2 * E + e];
    int dst = edges[b * 2 * E + E + e];
    atomicAdd(&C[(size_t)b * N * N + (size_t)dst * N + src], 1.0f);
}

// ---------------------------------------------------------------------------
// cp_pool: prod_out[b][r] = prod_n tanh( sum_k hn[b][n][k] * W[k][r] )
// hn = [h | 1], K1 = 513.  Block computes full N=128 x 128-r tile, K-tiled.
// threads: 256 = 16(ty:n) x 16(tx:r); micro-tile 8x8 per thread.
// ---------------------------------------------------------------------------
__global__ __launch_bounds__(256)
void cp_pool_kernel(const float* __restrict__ h,      // [B,N,D]
                    const float* __restrict__ W,      // [K1,R] (this layer)
                    float* __restrict__ prod_out)     // [B,R]  (this layer)
{
    const int b   = blockIdx.y;
    const int r0  = blockIdx.x * 128;
    const int tid = threadIdx.x;
    const int tx  = tid & 15;   // r sub
    const int ty  = tid >> 4;   // n sub

    __shared__ float As[128 * 17];   // [n][k], stride 17 (pad: avoids bank conflicts)
    __shared__ float Bs[16 * 128];   // [k][r]

    float acc[8][8];
#pragma unroll
    for (int i = 0; i < 8; ++i)
#pragma unroll
        for (int j = 0; j < 8; ++j) acc[i][j] = 0.f;

    const float* hb = h + (size_t)b * N * D;

    for (int k0 = 0; k0 < K1; k0 += 16) {
        // stage A: hn tile, 16 k x 128 n  -> As[n][k]
        {
            const int k  = tid & 15;
            const int n0 = tid >> 4;
            const int kk = k0 + k;
#pragma unroll
            for (int p = 0; p < 8; ++p) {
                const int n = n0 + p * 16;
                float v = 0.f;
                if (kk < D)       v = hb[n * D + kk];
                else if (kk == D) v = 1.0f;
                As[n * 17 + k] = v;
            }
        }
        // stage B: W tile, 16 k x 128 r -> Bs[k][r]
        {
            const int r  = tid & 127;
            const int kb = tid >> 7;   // 0..1
#pragma unroll
            for (int p = 0; p < 8; ++p) {
                const int k  = kb + p * 2;
                const int kk = k0 + k;
                Bs[k * 128 + r] = (kk < K1) ? W[(size_t)kk * R + r0 + r] : 0.f;
            }
        }
        __syncthreads();
#pragma unroll
        for (int k = 0; k < 16; ++k) {
            float a[8], bb[8];
#pragma unroll
            for (int i = 0; i < 8; ++i) a[i] = As[(ty + i * 16) * 17 + k];
#pragma unroll
            for (int j = 0; j < 8; ++j) bb[j] = Bs[k * 128 + tx + j * 16];
#pragma unroll
            for (int i = 0; i < 8; ++i)
#pragma unroll
                for (int j = 0; j < 8; ++j)
                    acc[i][j] = fmaf(a[i], bb[j], acc[i][j]);
        }
        __syncthreads();
    }

    // per-thread partial product over its 8 n values (n = ty + i*16)
    float part[8];
#pragma unroll
    for (int j = 0; j < 8; ++j) {
        float p = 1.f;
#pragma unroll
        for (int i = 0; i < 8; ++i) p *= tanhf(acc[i][j]);
        part[j] = p;
    }

    // reduce product across the 16 ty groups via LDS (reuse As: 2048 <= 128*17)
    float* red = As;
#pragma unroll
    for (int j = 0; j < 8; ++j) red[ty * 128 + tx + j * 16] = part[j];
    __syncthreads();
    if (tid < 128) {
        float p = 1.f;
#pragma unroll
        for (int t = 0; t < 16; ++t) p *= red[t * 128 + tid];
        prod_out[(size_t)b * R + r0 + tid] = p;
    }
}

// ---------------------------------------------------------------------------
// aggregate: h_out[b,n,d] = h_in[b,n,d] + sum_s C[b,n,s] * h_in[b,s,d]
// Block: 128 n x 64 d tile, K=128 in chunks of 32. 256 thr = 16x16, micro 8x4.
// ---------------------------------------------------------------------------
__global__ __launch_bounds__(256)
void aggregate_kernel(const float* __restrict__ h_in,  // [B,N,D]
                      const float* __restrict__ C,     // [B,N,N]
                      float* __restrict__ h_out)       // [B,N,D]
{
    const int b   = blockIdx.y;
    const int d0  = blockIdx.x * 64;
    const int tid = threadIdx.x;
    const int tx  = tid & 15;   // d sub
    const int ty  = tid >> 4;   // n sub

    __shared__ float Cs[128 * 33];  // [n][s], stride 33
    __shared__ float hs[32 * 64];   // [s][d]

    float acc[8][4];
#pragma unroll
    for (int i = 0; i < 8; ++i)
#pragma unroll
        for (int j = 0; j < 4; ++j) acc[i][j] = 0.f;

    const float* hb = h_in + (size_t)b * N * D;
    const float* Cb = C + (size_t)b * N * N;

    for (int s0 = 0; s0 < N; s0 += 32) {
        // stage Cs: 128 n x 32 s
        {
            const int s  = tid & 31;
            const int n0 = tid >> 5;   // 0..7
#pragma unroll
            for (int p = 0; p < 16; ++p) {
                const int n = n0 + p * 8;
                Cs[n * 33 + s] = Cb[n * N + s0 + s];
            }
        }
        // stage hs: 32 s x 64 d
        {
            const int d  = tid & 63;
            const int s1 = tid >> 6;   // 0..3
#pragma unroll
            for (int p = 0; p < 8; ++p) {
                const int s = s1 + p * 4;
                hs[s * 64 + d] = hb[(s0 + s) * D + d0 + d];
            }
        }
        __syncthreads();
#pragma unroll
        for (int s = 0; s < 32; ++s) {
            float a[8], bb[4];
#pragma unroll
            for (int i = 0; i < 8; ++i) a[i] = Cs[(ty + i * 16) * 33 + s];
#pragma unroll
            for (int j = 0; j < 4; ++j) bb[j] = hs[s * 64 + tx + j * 16];
#pragma unroll
            for (int i = 0; i < 8; ++i)
#pragma unroll
                for (int j = 0; j < 4; ++j)
                    acc[i][j] = fmaf(a[i], bb[j], acc[i][j]);
        }
        __syncthreads();
    }

    // h_out = h_in + agg
#pragma unroll
    for (int i = 0; i < 8; ++i) {
        const int n = ty + i * 16;
#pragma unroll
        for (int j = 0; j < 4; ++j) {
            const int d = d0 + tx + j * 16;
            h_out[(size_t)b * N * D + n * D + d] = hb[n * D + d] + acc[i][j];
        }
    }
}

// ---------------------------------------------------------------------------
// score: out[b][o] = sum_l ( lin_b[l][o] + sum_r prod[l][b][r]*lin_w[l][r][o] )
// ---------------------------------------------------------------------------
__global__ __launch_bounds__(256)
void score_kernel(const float* __restrict__ prod,   // [L,B,R]
                  const float* __restrict__ lin_w,  // [L,R,O]
                  const float* __restrict__ lin_b,  // [L,O]
                  float* __restrict__ out)          // [B,O]
{
    const int b   = blockIdx.x;
    const int tid = threadIdx.x;

    float acc[O];
#pragma unroll
    for (int o = 0; o < O; ++o) acc[o] = 0.f;

    for (int l = 0; l < L; ++l) {
        const float* pl = prod + ((size_t)l * B + b) * R;
        const float* wl = lin_w + (size_t)l * R * O;
        for (int r = tid; r < R; r += 256) {
            const float p = pl[r];
#pragma unroll
            for (int o = 0; o < O; ++o)
                acc[o] = fmaf(p, wl[r * O + o], acc[o]);
        }
    }

    __shared__ float sb[256];
    for (int o = 0; o < O; ++o) {
        sb[tid] = acc[o];
        __syncthreads();
        for (int off = 128; off > 0; off >>= 1) {
            if (tid < off) sb[tid] += sb[tid + off];
            __syncthreads();
        }
        if (tid == 0) {
            float bias = 0.f;
            for (int l = 0; l < L; ++l) bias += lin_b[l * O + o];
            out[b * O + o] = sb[0] + bias;
        }
        __syncthreads();
    }
}

// ---------------------------------------------------------------------------
extern "C" void kernel_launch(void* const* d_in, const int* in_sizes, int n_in,
                              void* d_out, int out_size, void* d_ws, size_t ws_size,
                              hipStream_t stream) {
    const float* x     = (const float*)d_in[0];   // [B,N,D]
    const int*   edges = (const int*)d_in[1];     // [B,2,E]
    const float* W_cp  = (const float*)d_in[2];   // [L,K1,R]
    const float* lin_w = (const float*)d_in[3];   // [L,R,O]
    const float* lin_b = (const float*)d_in[4];   // [L,O]
    float*       out   = (float*)d_out;           // [B,O]

    char* ws = (char*)d_ws;
    const size_t C_BYTES = (size_t)B * N * N * 4;   // 16 MiB
    const size_t H_BYTES = (size_t)B * N * D * 4;   // 64 MiB
    float* C    = (float*)ws;
    float* hA   = (float*)(ws + C_BYTES);
    float* hB   = (float*)(ws + C_BYTES + H_BYTES);
    float* prod = (float*)(ws + C_BYTES + 2 * H_BYTES);  // [L,B,R]

    // adjacency counts
    zero_kernel<<<1024, 256, 0, stream>>>(C, (size_t)B * N * N);
    fill_adj_kernel<<<(B * E + 255) / 256, 256, 0, stream>>>(edges, C);

    dim3 cpGrid(R / 128, B);
    dim3 agGrid(D / 64, B);

    // layer 0 on x
    cp_pool_kernel<<<cpGrid, 256, 0, stream>>>(x, W_cp, prod);

    const float* hprev = x;
    float* bufs[2] = {hA, hB};
    for (int l = 1; l < L; ++l) {
        float* hnext = bufs[(l - 1) & 1];
        aggregate_kernel<<<agGrid, 256, 0, stream>>>(hprev, C, hnext);
        cp_pool_kernel<<<cpGrid, 256, 0, stream>>>(
            hnext, W_cp + (size_t)l * K1 * R, prod + (size_t)l * B * R);
        hprev = hnext;
    }

    score_kernel<<<B, 256, 0, stream>>>(prod, lin_w, lin_b, out);
}

// Round 2
// 1286.853 us; speedup vs baseline: 3.2009x; 3.2009x over previous
//
#include <hip/hip_runtime.h>
#include <math.h>

#define B 256
#define N 128
#define E 2048
#define D 512
#define R 1024
#define O 10
#define L 5
#define BK 32

typedef unsigned short u16;
typedef unsigned int u32;
typedef __bf16 bf16x8 __attribute__((ext_vector_type(8)));
typedef u16 u16x8 __attribute__((ext_vector_type(8)));
typedef float floatx4 __attribute__((ext_vector_type(4)));

// ---- bf16 helpers (RNE) ----------------------------------------------------
__device__ inline u16 f2bf(float f) {
    union { float f; u32 u; } v; v.f = f;
    u32 u = v.u;
    return (u16)((u + 0x7fffu + ((u >> 16) & 1u)) >> 16);
}
__device__ inline float bf2f(u16 s) {
    union { u32 u; float f; } v; v.u = ((u32)s) << 16;
    return v.f;
}

// ---- async global->LDS, 16B per lane (HW: wave-uniform base + lane*16) -----
__device__ inline void gload16(const void* g, void* l) {
    __builtin_amdgcn_global_load_lds(
        (const __attribute__((address_space(1))) void*)g,
        (__attribute__((address_space(3))) void*)l, 16, 0, 0);
}

__device__ inline bf16x8 ldsfrag(const u16* p) {
    u16x8 v = *(const u16x8*)p;
    return __builtin_bit_cast(bf16x8, v);
}

// ---------------------------------------------------------------------------
__global__ void zero_kernel(float* __restrict__ p, size_t n) {
    size_t i = (size_t)blockIdx.x * blockDim.x + threadIdx.x;
    size_t stride = (size_t)gridDim.x * blockDim.x;
    for (; i < n; i += stride) p[i] = 0.f;
}

__global__ void fill_adj_kernel(const int* __restrict__ edges, float* __restrict__ C) {
    int idx = blockIdx.x * blockDim.x + threadIdx.x;
    if (idx >= B * E) return;
    int b = idx / E;
    int e = idx - b * E;
    int src = edges[b * 2 * E + e];
    int dst = edges[b * 2 * E + E + e];
    atomicAdd(&C[(size_t)b * N * N + (size_t)dst * N + src], 1.0f);
}

// ---------------------------------------------------------------------------
// split x (fp32) -> hi/lo bf16 pair, float4/uint2 vectorized
// ---------------------------------------------------------------------------
__global__ void split_kernel(const float4* __restrict__ x4,
                             uint2* __restrict__ hi4, uint2* __restrict__ lo4, size_t n4) {
    size_t i = (size_t)blockIdx.x * blockDim.x + threadIdx.x;
    size_t stride = (size_t)gridDim.x * blockDim.x;
    for (; i < n4; i += stride) {
        float4 v = x4[i];
        u16 h0 = f2bf(v.x), h1 = f2bf(v.y), h2 = f2bf(v.z), h3 = f2bf(v.w);
        uint2 hp; hp.x = (u32)h0 | ((u32)h1 << 16); hp.y = (u32)h2 | ((u32)h3 << 16);
        hi4[i] = hp;
        u16 l0 = f2bf(v.x - bf2f(h0)), l1 = f2bf(v.y - bf2f(h1));
        u16 l2 = f2bf(v.z - bf2f(h2)), l3 = f2bf(v.w - bf2f(h3));
        uint2 lp; lp.x = (u32)l0 | ((u32)l1 << 16); lp.y = (u32)l2 | ((u32)l3 << 16);
        lo4[i] = lp;
    }
}

// ---------------------------------------------------------------------------
// transpose+split W_cp[l][0:512][1024] fp32 -> Wt_hi/Wt_lo [l][1024 r][512 k] bf16
// grid (16 rtiles, 8 ktiles, L), 256 thr
// ---------------------------------------------------------------------------
__global__ __launch_bounds__(256)
void wt_split_kernel(const float* __restrict__ W_cp,
                     u16* __restrict__ Wt_hi, u16* __restrict__ Wt_lo) {
    __shared__ float t[64][65];
    const int l = blockIdx.z, k0 = blockIdx.y * 64, r0 = blockIdx.x * 64;
    const float* Wl = W_cp + (size_t)l * 513 * 1024;
    const int tx = threadIdx.x & 63, ty = threadIdx.x >> 6;
#pragma unroll
    for (int p = 0; p < 16; ++p) {
        int k = ty + p * 4;
        t[k][tx] = Wl[(size_t)(k0 + k) * 1024 + r0 + tx];
    }
    __syncthreads();
    u16* oh = Wt_hi + ((size_t)l * 1024 + r0) * 512 + k0;
    u16* ol = Wt_lo + ((size_t)l * 1024 + r0) * 512 + k0;
#pragma unroll
    for (int p = 0; p < 16; ++p) {
        int r = ty + p * 4;
        float v = t[tx][r];           // = W[k0+tx][r0+r]
        u16 hv = f2bf(v);
        oh[(size_t)r * 512 + tx] = hv;
        ol[(size_t)r * 512 + tx] = f2bf(v - bf2f(hv));
    }
}

// ---------------------------------------------------------------------------
// cp_pool via split-bf16 MFMA:
//  S[n][r] = sum_k h[n][k]*W[k][r]  (K=512), then tanh(S + Wbias[r]), prod over n.
//  Block: b = blockIdx.y, r-tile 128 = blockIdx.x. 4 waves, each 64x64 quadrant
//  of 4x4 16x16x32 MFMAs, 3 MFMAs per tile (hi*hi + hi*lo + lo*hi).
// ---------------------------------------------------------------------------
__global__ __launch_bounds__(256)
void cp_pool_mfma_kernel(const u16* __restrict__ h_hi, const u16* __restrict__ h_lo,
                         const u16* __restrict__ Wt_hi, const u16* __restrict__ Wt_lo,
                         const float* __restrict__ Wbias,   // [1024] fp32 (W row 512)
                         float* __restrict__ prod_out)      // [B][R] this layer
{
    __shared__ u16 As_hi[128 * BK], As_lo[128 * BK];
    __shared__ u16 Bs_hi[128 * BK], Bs_lo[128 * BK];
    __shared__ float red[2][128];

    const int b   = blockIdx.y;
    const int r0  = blockIdx.x * 128;
    const int tid = threadIdx.x;
    const int w    = tid >> 6;
    const int lane = tid & 63;
    const int rb = w & 1;     // row block (n)   0..1
    const int cb = w >> 1;    // col block (r)   0..1

    floatx4 acc[4][4];
#pragma unroll
    for (int i = 0; i < 4; ++i)
#pragma unroll
        for (int j = 0; j < 4; ++j)
#pragma unroll
            for (int k = 0; k < 4; ++k) acc[i][j][k] = 0.f;

    // staging: 8 issues of 1KB per buffer; this wave does issues w*2, w*2+1
    const int srow = w * 32 + (lane >> 2);     // it=0 source row (n or r)
    const int kofs = (lane & 3) * 8;           // k offset in elements
    const u16* gAh = h_hi + ((size_t)b * 128 + srow) * 512 + kofs;
    const u16* gAl = h_lo + ((size_t)b * 128 + srow) * 512 + kofs;
    const u16* gBh = Wt_hi + (size_t)(r0 + srow) * 512 + kofs;
    const u16* gBl = Wt_lo + (size_t)(r0 + srow) * 512 + kofs;

    const int am = rb * 64 + (lane & 15);      // A row within 128
    const int bn = cb * 64 + (lane & 15);      // B col within 128
    const int ko = (lane >> 4) * 8;            // frag k offset (quad*8)

    for (int k0 = 0; k0 < 512; k0 += BK) {
#pragma unroll
        for (int it = 0; it < 2; ++it) {
            const size_t go = (size_t)it * 16 * 512;
            const int ld = (w * 2 + it) * 512;
            gload16(gAh + go, As_hi + ld);
            gload16(gAl + go, As_lo + ld);
            gload16(gBh + go, Bs_hi + ld);
            gload16(gBl + go, Bs_lo + ld);
        }
        gAh += BK; gAl += BK; gBh += BK; gBl += BK;
        __syncthreads();

        bf16x8 ah[4], al[4], bh[4], bl[4];
#pragma unroll
        for (int t = 0; t < 4; ++t) {
            ah[t] = ldsfrag(&As_hi[(am + t * 16) * BK + ko]);
            al[t] = ldsfrag(&As_lo[(am + t * 16) * BK + ko]);
            bh[t] = ldsfrag(&Bs_hi[(bn + t * 16) * BK + ko]);
            bl[t] = ldsfrag(&Bs_lo[(bn + t * 16) * BK + ko]);
        }
#pragma unroll
        for (int i = 0; i < 4; ++i)
#pragma unroll
            for (int j = 0; j < 4; ++j) {
                acc[i][j] = __builtin_amdgcn_mfma_f32_16x16x32_bf16(al[i], bh[j], acc[i][j], 0, 0, 0);
                acc[i][j] = __builtin_amdgcn_mfma_f32_16x16x32_bf16(ah[i], bl[j], acc[i][j], 0, 0, 0);
                acc[i][j] = __builtin_amdgcn_mfma_f32_16x16x32_bf16(ah[i], bh[j], acc[i][j], 0, 0, 0);
            }
        __syncthreads();
    }

    // epilogue: +bias, tanh, product over n (M axis)
    const int quad = lane >> 4;
    const int c16  = lane & 15;
#pragma unroll
    for (int tj = 0; tj < 4; ++tj) {
        const int c = cb * 64 + tj * 16 + c16;       // col within 128
        const float bias = Wbias[r0 + c];
        float p = 1.f;
#pragma unroll
        for (int ti = 0; ti < 4; ++ti)
#pragma unroll
            for (int ri = 0; ri < 4; ++ri)
                p *= tanhf(acc[ti][tj][ri] + bias);
        // product across the 4 quads (rows quad*4+ri within each 16-tile)
        p *= __shfl_xor(p, 16, 64);
        p *= __shfl_xor(p, 32, 64);
        if (quad == 0) red[rb][c] = p;
    }
    __syncthreads();
    if (tid < 128)
        prod_out[(size_t)b * R + r0 + tid] = red[0][tid] * red[1][tid];
}

// ---------------------------------------------------------------------------
// aggregate on bf16 hi/lo pairs: h_out = h_in + C @ h_in
// Block: 128 n x 64 d tile; 256 thr = 16x16, micro 8x4.
// ---------------------------------------------------------------------------
__global__ __launch_bounds__(256)
void aggregate_kernel(const u16* __restrict__ hi_in, const u16* __restrict__ lo_in,
                      const float* __restrict__ C,
                      u16* __restrict__ hi_out, u16* __restrict__ lo_out)
{
    const int b   = blockIdx.y;
    const int d0  = blockIdx.x * 64;
    const int tid = threadIdx.x;
    const int tx  = tid & 15;   // d sub
    const int ty  = tid >> 4;   // n sub

    __shared__ float Cs[128 * 33];
    __shared__ float hs[32 * 64];

    float acc[8][4];
#pragma unroll
    for (int i = 0; i < 8; ++i)
#pragma unroll
        for (int j = 0; j < 4; ++j) acc[i][j] = 0.f;

    const size_t hb = (size_t)b * N * D;
    const float* Cb = C + (size_t)b * N * N;

    for (int s0 = 0; s0 < N; s0 += 32) {
        {
            const int s  = tid & 31;
            const int n0 = tid >> 5;
#pragma unroll
            for (int p = 0; p < 16; ++p) {
                const int n = n0 + p * 8;
                Cs[n * 33 + s] = Cb[n * N + s0 + s];
            }
        }
        {
            const int d  = tid & 63;
            const int s1 = tid >> 6;
#pragma unroll
            for (int p = 0; p < 8; ++p) {
                const int s = s1 + p * 4;
                size_t idx = hb + (size_t)(s0 + s) * D + d0 + d;
                hs[s * 64 + d] = bf2f(hi_in[idx]) + bf2f(lo_in[idx]);
            }
        }
        __syncthreads();
#pragma unroll
        for (int s = 0; s < 32; ++s) {
            float a[8], bb[4];
#pragma unroll
            for (int i = 0; i < 8; ++i) a[i] = Cs[(ty + i * 16) * 33 + s];
#pragma unroll
            for (int j = 0; j < 4; ++j) bb[j] = hs[s * 64 + tx + j * 16];
#pragma unroll
            for (int i = 0; i < 8; ++i)
#pragma unroll
                for (int j = 0; j < 4; ++j)
                    acc[i][j] = fmaf(a[i], bb[j], acc[i][j]);
        }
        __syncthreads();
    }

#pragma unroll
    for (int i = 0; i < 8; ++i) {
        const int n = ty + i * 16;
#pragma unroll
        for (int j = 0; j < 4; ++j) {
            const int d = d0 + tx + j * 16;
            size_t o = hb + (size_t)n * D + d;
            float v = bf2f(hi_in[o]) + bf2f(lo_in[o]) + acc[i][j];
            u16 hv = f2bf(v);
            hi_out[o] = hv;
            lo_out[o] = f2bf(v - bf2f(hv));
        }
    }
}

// ---------------------------------------------------------------------------
__global__ __launch_bounds__(256)
void score_kernel(const float* __restrict__ prod,   // [L,B,R]
                  const float* __restrict__ lin_w,  // [L,R,O]
                  const float* __restrict__ lin_b,  // [L,O]
                  float* __restrict__ out)          // [B,O]
{
    const int b   = blockIdx.x;
    const int tid = threadIdx.x;

    float acc[O];
#pragma unroll
    for (int o = 0; o < O; ++o) acc[o] = 0.f;

    for (int l = 0; l < L; ++l) {
        const float* pl = prod + ((size_t)l * B + b) * R;
        const float* wl = lin_w + (size_t)l * R * O;
        for (int r = tid; r < R; r += 256) {
            const float p = pl[r];
#pragma unroll
            for (int o = 0; o < O; ++o)
                acc[o] = fmaf(p, wl[r * O + o], acc[o]);
        }
    }

    __shared__ float sb[256];
    for (int o = 0; o < O; ++o) {
        sb[tid] = acc[o];
        __syncthreads();
        for (int off = 128; off > 0; off >>= 1) {
            if (tid < off) sb[tid] += sb[tid + off];
            __syncthreads();
        }
        if (tid == 0) {
            float bias = 0.f;
            for (int l = 0; l < L; ++l) bias += lin_b[l * O + o];
            out[b * O + o] = sb[0] + bias;
        }
        __syncthreads();
    }
}

// ---------------------------------------------------------------------------
extern "C" void kernel_launch(void* const* d_in, const int* in_sizes, int n_in,
                              void* d_out, int out_size, void* d_ws, size_t ws_size,
                              hipStream_t stream) {
    const float* x     = (const float*)d_in[0];   // [B,N,D]
    const int*   edges = (const int*)d_in[1];     // [B,2,E]
    const float* W_cp  = (const float*)d_in[2];   // [L,513,1024]
    const float* lin_w = (const float*)d_in[3];   // [L,R,O]
    const float* lin_b = (const float*)d_in[4];   // [L,O]
    float*       out   = (float*)d_out;           // [B,O]

    char* ws = (char*)d_ws;
    const size_t C_BYTES  = (size_t)B * N * N * 4;        // 16.8 MB
    const size_t HH_BYTES = (size_t)B * N * D * 2;        // 33.6 MB per bf16 h buffer
    const size_t WT_BYTES = (size_t)L * 1024 * 512 * 2;   // 5.24 MB

    float* C     = (float*)ws;                    ws += C_BYTES;
    u16*   hiA   = (u16*)ws;                      ws += HH_BYTES;
    u16*   loA   = (u16*)ws;                      ws += HH_BYTES;
    u16*   hiB   = (u16*)ws;                      ws += HH_BYTES;
    u16*   loB   = (u16*)ws;                      ws += HH_BYTES;
    u16*   Wt_hi = (u16*)ws;                      ws += WT_BYTES;
    u16*   Wt_lo = (u16*)ws;                      ws += WT_BYTES;
    float* prod  = (float*)ws;                    // [L,B,R] 5.24 MB

    // adjacency counts
    zero_kernel<<<1024, 256, 0, stream>>>(C, (size_t)B * N * N);
    fill_adj_kernel<<<(B * E + 255) / 256, 256, 0, stream>>>(edges, C);

    // W transpose + split (once)
    wt_split_kernel<<<dim3(16, 8, L), 256, 0, stream>>>(W_cp, Wt_hi, Wt_lo);

    // x -> hi/lo
    split_kernel<<<2048, 256, 0, stream>>>((const float4*)x, (uint2*)hiA, (uint2*)loA,
                                           (size_t)B * N * D / 4);

    dim3 cpGrid(R / 128, B);
    dim3 agGrid(D / 64, B);

    // layer 0
    cp_pool_mfma_kernel<<<cpGrid, 256, 0, stream>>>(
        hiA, loA, Wt_hi, Wt_lo, W_cp + (size_t)512 * 1024, prod);

    const u16* phi = hiA; const u16* plo = loA;
    u16* bhi[2] = {hiB, hiA};
    u16* blo[2] = {loB, loA};
    for (int l = 1; l < L; ++l) {
        u16* nhi = bhi[(l - 1) & 1];
        u16* nlo = blo[(l - 1) & 1];
        aggregate_kernel<<<agGrid, 256, 0, stream>>>(phi, plo, C, nhi, nlo);
        cp_pool_mfma_kernel<<<cpGrid, 256, 0, stream>>>(
            nhi, nlo,
            Wt_hi + (size_t)l * 1024 * 512, Wt_lo + (size_t)l * 1024 * 512,
            W_cp + ((size_t)l * 513 + 512) * 1024,
            prod + (size_t)l * B * R);
        phi = nhi; plo = nlo;
    }

    score_kernel<<<B, 256, 0, stream>>>(prod, lin_w, lin_b, out);
}

// Round 3
// 980.231 us; speedup vs baseline: 4.2021x; 1.3128x over previous
//
#include <hip/hip_runtime.h>
#include <math.h>

#define B 256
#define N 128
#define E 2048
#define D 512
#define R 1024
#define O 10
#define L 5
#define BK 32

typedef unsigned short u16;
typedef unsigned int u32;
typedef __bf16 bf16x8 __attribute__((ext_vector_type(8)));
typedef u16 u16x8 __attribute__((ext_vector_type(8)));
typedef float floatx4 __attribute__((ext_vector_type(4)));

// ---- bf16 helpers (RNE) ----------------------------------------------------
__device__ inline u16 f2bf(float f) {
    union { float f; u32 u; } v; v.f = f;
    u32 u = v.u;
    return (u16)((u + 0x7fffu + ((u >> 16) & 1u)) >> 16);
}
__device__ inline float bf2f(u16 s) {
    union { u32 u; float f; } v; v.u = ((u32)s) << 16;
    return v.f;
}

__device__ inline float fast_tanh(float x) {
    // tanh(x) = 1 - 2/(exp(2x)+1); exact at +-inf saturation, ~1e-6 abs err
    return 1.0f - 2.0f / (__expf(2.0f * x) + 1.0f);
}

// ---- async global->LDS, 16B per lane (HW: wave-uniform base + lane*16) -----
__device__ inline void gload16(const void* g, void* l) {
    __builtin_amdgcn_global_load_lds(
        (const __attribute__((address_space(1))) void*)g,
        (__attribute__((address_space(3))) void*)l, 16, 0, 0);
}

__device__ inline bf16x8 ldsfrag(const u16* p) {
    u16x8 v = *(const u16x8*)p;
    return __builtin_bit_cast(bf16x8, v);
}

// ---------------------------------------------------------------------------
__global__ void zero_kernel(float* __restrict__ p, size_t n) {
    size_t i = (size_t)blockIdx.x * blockDim.x + threadIdx.x;
    size_t stride = (size_t)gridDim.x * blockDim.x;
    for (; i < n; i += stride) p[i] = 0.f;
}

__global__ void fill_adj_kernel(const int* __restrict__ edges, float* __restrict__ C) {
    int idx = blockIdx.x * blockDim.x + threadIdx.x;
    if (idx >= B * E) return;
    int b = idx / E;
    int e = idx - b * E;
    int src = edges[b * 2 * E + e];
    int dst = edges[b * 2 * E + E + e];
    atomicAdd(&C[(size_t)b * N * N + (size_t)dst * N + src], 1.0f);
}

// ---------------------------------------------------------------------------
// split x (fp32) -> hi/lo bf16 pair
// ---------------------------------------------------------------------------
__global__ void split_kernel(const float4* __restrict__ x4,
                             uint2* __restrict__ hi4, uint2* __restrict__ lo4, size_t n4) {
    size_t i = (size_t)blockIdx.x * blockDim.x + threadIdx.x;
    size_t stride = (size_t)gridDim.x * blockDim.x;
    for (; i < n4; i += stride) {
        float4 v = x4[i];
        u16 h0 = f2bf(v.x), h1 = f2bf(v.y), h2 = f2bf(v.z), h3 = f2bf(v.w);
        uint2 hp; hp.x = (u32)h0 | ((u32)h1 << 16); hp.y = (u32)h2 | ((u32)h3 << 16);
        hi4[i] = hp;
        u16 l0 = f2bf(v.x - bf2f(h0)), l1 = f2bf(v.y - bf2f(h1));
        u16 l2 = f2bf(v.z - bf2f(h2)), l3 = f2bf(v.w - bf2f(h3));
        uint2 lp; lp.x = (u32)l0 | ((u32)l1 << 16); lp.y = (u32)l2 | ((u32)l3 << 16);
        lo4[i] = lp;
    }
}

// ---------------------------------------------------------------------------
// transpose+split W_cp[l][0:512][1024] fp32 -> Wt_hi/Wt_lo [l][1024 r][512 k]
// ---------------------------------------------------------------------------
__global__ __launch_bounds__(256)
void wt_split_kernel(const float* __restrict__ W_cp,
                     u16* __restrict__ Wt_hi, u16* __restrict__ Wt_lo) {
    __shared__ float t[64][65];
    const int l = blockIdx.z, k0 = blockIdx.y * 64, r0 = blockIdx.x * 64;
    const float* Wl = W_cp + (size_t)l * 513 * 1024;
    const int tx = threadIdx.x & 63, ty = threadIdx.x >> 6;
#pragma unroll
    for (int p = 0; p < 16; ++p) {
        int k = ty + p * 4;
        t[k][tx] = Wl[(size_t)(k0 + k) * 1024 + r0 + tx];
    }
    __syncthreads();
    u16* oh = Wt_hi + ((size_t)l * 1024 + r0) * 512 + k0;
    u16* ol = Wt_lo + ((size_t)l * 1024 + r0) * 512 + k0;
#pragma unroll
    for (int p = 0; p < 16; ++p) {
        int r = ty + p * 4;
        float v = t[tx][r];
        u16 hv = f2bf(v);
        oh[(size_t)r * 512 + tx] = hv;
        ol[(size_t)r * 512 + tx] = f2bf(v - bf2f(hv));
    }
}

// ---------------------------------------------------------------------------
// cp_pool via split-bf16 MFMA. 1D grid of 2048 blocks, XCD-aware decode:
//   xcd = flat&7 handles b in [32*xcd, 32*xcd+32), 8 consecutive blocks = one b.
// LDS k-chunk XOR swizzle: chunk c of row r stored at c ^ ((r>>1)&3)
//   -> ds_read_b128 conflict-free (2-deep per 16-lane phase).
// ---------------------------------------------------------------------------
__global__ __launch_bounds__(256)
void cp_pool_mfma_kernel(const u16* __restrict__ h_hi, const u16* __restrict__ h_lo,
                         const u16* __restrict__ Wt_hi, const u16* __restrict__ Wt_lo,
                         const float* __restrict__ Wbias,   // [1024] fp32 (W row 512)
                         float* __restrict__ prod_out)      // [B][R] this layer
{
    __shared__ u16 As_hi[128 * BK], As_lo[128 * BK];
    __shared__ u16 Bs_hi[128 * BK], Bs_lo[128 * BK];
    __shared__ float red[2][128];

    const int flat = blockIdx.x;
    const int s    = flat >> 3;
    const int b    = (flat & 7) * 32 + (s >> 3);
    const int r0   = (s & 7) * 128;

    const int tid = threadIdx.x;
    const int w    = tid >> 6;
    const int lane = tid & 63;
    const int rb = w & 1;     // row block (n)
    const int cb = w >> 1;    // col block (r)

    floatx4 acc[4][4];
#pragma unroll
    for (int i = 0; i < 4; ++i)
#pragma unroll
        for (int j = 0; j < 4; ++j)
#pragma unroll
            for (int k = 0; k < 4; ++k) acc[i][j][k] = 0.f;

    // staging: 8 issues of 1KB per buffer; wave w does issues w*2, w*2+1.
    // source k-chunk permuted: chunk written at LDS pos c (=lane&3) of row
    // (lane>>2) comes from global chunk c ^ ((row>>1)&3) = (lane&3)^((lane>>3)&3)
    const int srow = w * 32 + (lane >> 2);
    const int kswz = (((lane & 3) ^ ((lane >> 3) & 3)) * 8);
    const u16* gAh = h_hi + ((size_t)b * 128 + srow) * 512 + kswz;
    const u16* gAl = h_lo + ((size_t)b * 128 + srow) * 512 + kswz;
    const u16* gBh = Wt_hi + (size_t)(r0 + srow) * 512 + kswz;
    const u16* gBl = Wt_lo + (size_t)(r0 + srow) * 512 + kswz;

    const int am = rb * 64 + (lane & 15);      // A row within 128
    const int bn = cb * 64 + (lane & 15);      // B col within 128
    // frag k offset: want global chunk q=lane>>4 of row; stored at q ^ ((row>>1)&3)
    const int ko = (((lane >> 4) ^ ((lane >> 1) & 3)) * 8);

    for (int k0 = 0; k0 < 512; k0 += BK) {
#pragma unroll
        for (int it = 0; it < 2; ++it) {
            const size_t go = (size_t)it * 16 * 512;
            const int ld = (w * 2 + it) * 512;
            gload16(gAh + go, As_hi + ld);
            gload16(gAl + go, As_lo + ld);
            gload16(gBh + go, Bs_hi + ld);
            gload16(gBl + go, Bs_lo + ld);
        }
        gAh += BK; gAl += BK; gBh += BK; gBl += BK;
        __syncthreads();

        bf16x8 ah[4], al[4], bh[4], bl[4];
#pragma unroll
        for (int t = 0; t < 4; ++t) {
            ah[t] = ldsfrag(&As_hi[(am + t * 16) * BK + ko]);
            al[t] = ldsfrag(&As_lo[(am + t * 16) * BK + ko]);
            bh[t] = ldsfrag(&Bs_hi[(bn + t * 16) * BK + ko]);
            bl[t] = ldsfrag(&Bs_lo[(bn + t * 16) * BK + ko]);
        }
#pragma unroll
        for (int i = 0; i < 4; ++i)
#pragma unroll
            for (int j = 0; j < 4; ++j) {
                acc[i][j] = __builtin_amdgcn_mfma_f32_16x16x32_bf16(al[i], bh[j], acc[i][j], 0, 0, 0);
                acc[i][j] = __builtin_amdgcn_mfma_f32_16x16x32_bf16(ah[i], bl[j], acc[i][j], 0, 0, 0);
                acc[i][j] = __builtin_amdgcn_mfma_f32_16x16x32_bf16(ah[i], bh[j], acc[i][j], 0, 0, 0);
            }
        __syncthreads();
    }

    // epilogue: +bias, tanh, product over n (M axis)
    const int quad = lane >> 4;
    const int c16  = lane & 15;
#pragma unroll
    for (int tj = 0; tj < 4; ++tj) {
        const int c = cb * 64 + tj * 16 + c16;
        const float bias = Wbias[r0 + c];
        float p = 1.f;
#pragma unroll
        for (int ti = 0; ti < 4; ++ti)
#pragma unroll
            for (int ri = 0; ri < 4; ++ri)
                p *= fast_tanh(acc[ti][tj][ri] + bias);
        p *= __shfl_xor(p, 16, 64);
        p *= __shfl_xor(p, 32, 64);
        if (quad == 0) red[rb][c] = p;
    }
    __syncthreads();
    if (tid < 128)
        prod_out[(size_t)b * R + r0 + tid] = red[0][tid] * red[1][tid];
}

// ---------------------------------------------------------------------------
// aggregate on bf16 hi/lo pairs: h_out = h_in + C @ h_in
// 1D grid 2048, same XCD decode (b from flat&7 partition). 128n x 64d tile.
// ---------------------------------------------------------------------------
__global__ __launch_bounds__(256)
void aggregate_kernel(const u16* __restrict__ hi_in, const u16* __restrict__ lo_in,
                      const float* __restrict__ C,
                      u16* __restrict__ hi_out, u16* __restrict__ lo_out)
{
    const int flat = blockIdx.x;
    const int s0i  = flat >> 3;
    const int b    = (flat & 7) * 32 + (s0i >> 3);
    const int d0   = (s0i & 7) * 64;

    const int tid = threadIdx.x;
    const int tx  = tid & 15;   // d sub
    const int ty  = tid >> 4;   // n sub

    __shared__ float Cs[128 * 33];
    __shared__ float hs[32 * 64];

    float acc[8][4];
#pragma unroll
    for (int i = 0; i < 8; ++i)
#pragma unroll
        for (int j = 0; j < 4; ++j) acc[i][j] = 0.f;

    const size_t hb = (size_t)b * N * D;
    const float* Cb = C + (size_t)b * N * N;

    for (int s0 = 0; s0 < N; s0 += 32) {
        {
            const int ss  = tid & 31;
            const int n0 = tid >> 5;
#pragma unroll
            for (int p = 0; p < 16; ++p) {
                const int n = n0 + p * 8;
                Cs[n * 33 + ss] = Cb[n * N + s0 + ss];
            }
        }
        {
            // u32-vectorized: each thread loads 2 consecutive d
            const int d2  = (tid & 31) * 2;
            const int s1  = tid >> 5;     // 0..7
#pragma unroll
            for (int p = 0; p < 4; ++p) {
                const int ss = s1 + p * 8;
                size_t idx = hb + (size_t)(s0 + ss) * D + d0 + d2;
                u32 hp = *(const u32*)&hi_in[idx];
                u32 lp = *(const u32*)&lo_in[idx];
                hs[ss * 64 + d2]     = bf2f((u16)hp) + bf2f((u16)lp);
                hs[ss * 64 + d2 + 1] = bf2f((u16)(hp >> 16)) + bf2f((u16)(lp >> 16));
            }
        }
        __syncthreads();
#pragma unroll
        for (int ss = 0; ss < 32; ++ss) {
            float a[8], bb[4];
#pragma unroll
            for (int i = 0; i < 8; ++i) a[i] = Cs[(ty + i * 16) * 33 + ss];
#pragma unroll
            for (int j = 0; j < 4; ++j) bb[j] = hs[ss * 64 + tx + j * 16];
#pragma unroll
            for (int i = 0; i < 8; ++i)
#pragma unroll
                for (int j = 0; j < 4; ++j)
                    acc[i][j] = fmaf(a[i], bb[j], acc[i][j]);
        }
        __syncthreads();
    }

#pragma unroll
    for (int i = 0; i < 8; ++i) {
        const int n = ty + i * 16;
#pragma unroll
        for (int j = 0; j < 4; ++j) {
            const int d = d0 + tx + j * 16;
            size_t o = hb + (size_t)n * D + d;
            float v = bf2f(hi_in[o]) + bf2f(lo_in[o]) + acc[i][j];
            u16 hv = f2bf(v);
            hi_out[o] = hv;
            lo_out[o] = f2bf(v - bf2f(hv));
        }
    }
}

// ---------------------------------------------------------------------------
__global__ __launch_bounds__(256)
void score_kernel(const float* __restrict__ prod,   // [L,B,R]
                  const float* __restrict__ lin_w,  // [L,R,O]
                  const float* __restrict__ lin_b,  // [L,O]
                  float* __restrict__ out)          // [B,O]
{
    const int b   = blockIdx.x;
    const int tid = threadIdx.x;

    float acc[O];
#pragma unroll
    for (int o = 0; o < O; ++o) acc[o] = 0.f;

    for (int l = 0; l < L; ++l) {
        const float* pl = prod + ((size_t)l * B + b) * R;
        const float* wl = lin_w + (size_t)l * R * O;
        for (int r = tid; r < R; r += 256) {
            const float p = pl[r];
#pragma unroll
            for (int o = 0; o < O; ++o)
                acc[o] = fmaf(p, wl[r * O + o], acc[o]);
        }
    }

    __shared__ float sb[256];
    for (int o = 0; o < O; ++o) {
        sb[tid] = acc[o];
        __syncthreads();
        for (int off = 128; off > 0; off >>= 1) {
            if (tid < off) sb[tid] += sb[tid + off];
            __syncthreads();
        }
        if (tid == 0) {
            float bias = 0.f;
            for (int l = 0; l < L; ++l) bias += lin_b[l * O + o];
            out[b * O + o] = sb[0] + bias;
        }
        __syncthreads();
    }
}

// ---------------------------------------------------------------------------
extern "C" void kernel_launch(void* const* d_in, const int* in_sizes, int n_in,
                              void* d_out, int out_size, void* d_ws, size_t ws_size,
                              hipStream_t stream) {
    const float* x     = (const float*)d_in[0];   // [B,N,D]
    const int*   edges = (const int*)d_in[1];     // [B,2,E]
    const float* W_cp  = (const float*)d_in[2];   // [L,513,1024]
    const float* lin_w = (const float*)d_in[3];   // [L,R,O]
    const float* lin_b = (const float*)d_in[4];   // [L,O]
    float*       out   = (float*)d_out;           // [B,O]

    char* ws = (char*)d_ws;
    const size_t C_BYTES  = (size_t)B * N * N * 4;        // 16.8 MB
    const size_t HH_BYTES = (size_t)B * N * D * 2;        // 33.6 MB
    const size_t WT_BYTES = (size_t)L * 1024 * 512 * 2;   // 5.24 MB

    float* C     = (float*)ws;                    ws += C_BYTES;
    u16*   hiA   = (u16*)ws;                      ws += HH_BYTES;
    u16*   loA   = (u16*)ws;                      ws += HH_BYTES;
    u16*   hiB   = (u16*)ws;                      ws += HH_BYTES;
    u16*   loB   = (u16*)ws;                      ws += HH_BYTES;
    u16*   Wt_hi = (u16*)ws;                      ws += WT_BYTES;
    u16*   Wt_lo = (u16*)ws;                      ws += WT_BYTES;
    float* prod  = (float*)ws;                    // [L,B,R] 5.24 MB

    zero_kernel<<<1024, 256, 0, stream>>>(C, (size_t)B * N * N);
    fill_adj_kernel<<<(B * E + 255) / 256, 256, 0, stream>>>(edges, C);
    wt_split_kernel<<<dim3(16, 8, L), 256, 0, stream>>>(W_cp, Wt_hi, Wt_lo);
    split_kernel<<<2048, 256, 0, stream>>>((const float4*)x, (uint2*)hiA, (uint2*)loA,
                                           (size_t)B * N * D / 4);

    // layer 0
    cp_pool_mfma_kernel<<<2048, 256, 0, stream>>>(
        hiA, loA, Wt_hi, Wt_lo, W_cp + (size_t)512 * 1024, prod);

    const u16* phi = hiA; const u16* plo = loA;
    u16* bhi[2] = {hiB, hiA};
    u16* blo[2] = {loB, loA};
    for (int l = 1; l < L; ++l) {
        u16* nhi = bhi[(l - 1) & 1];
        u16* nlo = blo[(l - 1) & 1];
        aggregate_kernel<<<2048, 256, 0, stream>>>(phi, plo, C, nhi, nlo);
        cp_pool_mfma_kernel<<<2048, 256, 0, stream>>>(
            nhi, nlo,
            Wt_hi + (size_t)l * 1024 * 512, Wt_lo + (size_t)l * 1024 * 512,
            W_cp + ((size_t)l * 513 + 512) * 1024,
            prod + (size_t)l * B * R);
        phi = nhi; plo = nlo;
    }

    score_kernel<<<B, 256, 0, stream>>>(prod, lin_w, lin_b, out);
}

// Round 4
// 813.875 us; speedup vs baseline: 5.0610x; 1.2044x over previous
//
#include <hip/hip_runtime.h>
#include <math.h>

#define B 256
#define N 128
#define E 2048
#define D 512
#define R 1024
#define O 10
#define L 5
#define BK 32

typedef unsigned short u16;
typedef unsigned int u32;
typedef __bf16 bf16x8 __attribute__((ext_vector_type(8)));
typedef u16 u16x8 __attribute__((ext_vector_type(8)));
typedef float floatx4 __attribute__((ext_vector_type(4)));

// ---- bf16 helpers (RNE) ----------------------------------------------------
__device__ inline u16 f2bf(float f) {
    union { float f; u32 u; } v; v.f = f;
    u32 u = v.u;
    return (u16)((u + 0x7fffu + ((u >> 16) & 1u)) >> 16);
}
__device__ inline float bf2f(u16 s) {
    union { u32 u; float f; } v; v.u = ((u32)s) << 16;
    return v.f;
}

__device__ inline float fast_tanh(float x) {
    return 1.0f - 2.0f / (__expf(2.0f * x) + 1.0f);
}

// ---- async global->LDS, 16B per lane ---------------------------------------
__device__ inline void gload16(const void* g, void* l) {
    __builtin_amdgcn_global_load_lds(
        (const __attribute__((address_space(1))) void*)g,
        (__attribute__((address_space(3))) void*)l, 16, 0, 0);
}

__device__ inline bf16x8 ldsfrag(const u16* p) {
    u16x8 v = *(const u16x8*)p;
    return __builtin_bit_cast(bf16x8, v);
}

// ---------------------------------------------------------------------------
__global__ void zero_kernel(float* __restrict__ p, size_t n) {
    size_t i = (size_t)blockIdx.x * blockDim.x + threadIdx.x;
    size_t stride = (size_t)gridDim.x * blockDim.x;
    for (; i < n; i += stride) p[i] = 0.f;
}

__global__ void fill_adj_kernel(const int* __restrict__ edges, float* __restrict__ C) {
    int idx = blockIdx.x * blockDim.x + threadIdx.x;
    if (idx >= B * E) return;
    int b = idx / E;
    int e = idx - b * E;
    int src = edges[b * 2 * E + e];
    int dst = edges[b * 2 * E + E + e];
    atomicAdd(&C[(size_t)b * N * N + (size_t)dst * N + src], 1.0f);
}

// C' = C + I  (after fill_adj; stream-ordered so no race)
__global__ void diag_kernel(float* __restrict__ C) {
    int idx = blockIdx.x * blockDim.x + threadIdx.x;
    if (idx >= B * N) return;
    C[(size_t)(idx >> 7) * N * N + (size_t)(idx & 127) * 129] += 1.0f;
}

// C fp32 -> bf16 (counts are small ints: exact)
__global__ void cbf_kernel(const float4* __restrict__ C4, ushort4* __restrict__ o, size_t n4) {
    size_t i = (size_t)blockIdx.x * blockDim.x + threadIdx.x;
    size_t stride = (size_t)gridDim.x * blockDim.x;
    for (; i < n4; i += stride) {
        float4 v = C4[i];
        ushort4 r;
        r.x = f2bf(v.x); r.y = f2bf(v.y); r.z = f2bf(v.z); r.w = f2bf(v.w);
        o[i] = r;
    }
}

// ---------------------------------------------------------------------------
// split x (fp32) -> hi/lo bf16 pair
// ---------------------------------------------------------------------------
__global__ void split_kernel(const float4* __restrict__ x4,
                             uint2* __restrict__ hi4, uint2* __restrict__ lo4, size_t n4) {
    size_t i = (size_t)blockIdx.x * blockDim.x + threadIdx.x;
    size_t stride = (size_t)gridDim.x * blockDim.x;
    for (; i < n4; i += stride) {
        float4 v = x4[i];
        u16 h0 = f2bf(v.x), h1 = f2bf(v.y), h2 = f2bf(v.z), h3 = f2bf(v.w);
        uint2 hp; hp.x = (u32)h0 | ((u32)h1 << 16); hp.y = (u32)h2 | ((u32)h3 << 16);
        hi4[i] = hp;
        u16 l0 = f2bf(v.x - bf2f(h0)), l1 = f2bf(v.y - bf2f(h1));
        u16 l2 = f2bf(v.z - bf2f(h2)), l3 = f2bf(v.w - bf2f(h3));
        uint2 lp; lp.x = (u32)l0 | ((u32)l1 << 16); lp.y = (u32)l2 | ((u32)l3 << 16);
        lo4[i] = lp;
    }
}

// ---------------------------------------------------------------------------
// transpose+split W_cp[l][0:512][1024] fp32 -> Wt_hi/Wt_lo [l][1024 r][512 k]
// ---------------------------------------------------------------------------
__global__ __launch_bounds__(256)
void wt_split_kernel(const float* __restrict__ W_cp,
                     u16* __restrict__ Wt_hi, u16* __restrict__ Wt_lo) {
    __shared__ float t[64][65];
    const int l = blockIdx.z, k0 = blockIdx.y * 64, r0 = blockIdx.x * 64;
    const float* Wl = W_cp + (size_t)l * 513 * 1024;
    const int tx = threadIdx.x & 63, ty = threadIdx.x >> 6;
#pragma unroll
    for (int p = 0; p < 16; ++p) {
        int k = ty + p * 4;
        t[k][tx] = Wl[(size_t)(k0 + k) * 1024 + r0 + tx];
    }
    __syncthreads();
    u16* oh = Wt_hi + ((size_t)l * 1024 + r0) * 512 + k0;
    u16* ol = Wt_lo + ((size_t)l * 1024 + r0) * 512 + k0;
#pragma unroll
    for (int p = 0; p < 16; ++p) {
        int r = ty + p * 4;
        float v = t[tx][r];
        u16 hv = f2bf(v);
        oh[(size_t)r * 512 + tx] = hv;
        ol[(size_t)r * 512 + tx] = f2bf(v - bf2f(hv));
    }
}

// ---------------------------------------------------------------------------
// cp_pool via split-bf16 MFMA, issue-after-barrier pipelined K-loop.
// Per step: B1 (drain prev loads) -> ds_read frags -> B2 (buffers dead) ->
// issue next step's loads (fly under MFMA burst) -> 48 MFMA/wave.
// ---------------------------------------------------------------------------
__global__ __launch_bounds__(256)
void cp_pool_mfma_kernel(const u16* __restrict__ h_hi, const u16* __restrict__ h_lo,
                         const u16* __restrict__ Wt_hi, const u16* __restrict__ Wt_lo,
                         const float* __restrict__ Wbias,   // [1024] fp32 (W row 512)
                         float* __restrict__ prod_out)      // [B][R] this layer
{
    __shared__ u16 As_hi[128 * BK], As_lo[128 * BK];
    __shared__ u16 Bs_hi[128 * BK], Bs_lo[128 * BK];
    __shared__ float red[2][128];

    const int flat = blockIdx.x;
    const int s    = flat >> 3;
    const int b    = (flat & 7) * 32 + (s >> 3);
    const int r0   = (s & 7) * 128;

    const int tid = threadIdx.x;
    const int w    = tid >> 6;
    const int lane = tid & 63;
    const int rb = w & 1;
    const int cb = w >> 1;

    floatx4 acc[4][4];
#pragma unroll
    for (int i = 0; i < 4; ++i)
#pragma unroll
        for (int j = 0; j < 4; ++j)
#pragma unroll
            for (int k = 0; k < 4; ++k) acc[i][j][k] = 0.f;

    const int srow = w * 32 + (lane >> 2);
    const int kswz = (((lane & 3) ^ ((lane >> 3) & 3)) * 8);
    const u16* gAh = h_hi + ((size_t)b * 128 + srow) * 512 + kswz;
    const u16* gAl = h_lo + ((size_t)b * 128 + srow) * 512 + kswz;
    const u16* gBh = Wt_hi + (size_t)(r0 + srow) * 512 + kswz;
    const u16* gBl = Wt_lo + (size_t)(r0 + srow) * 512 + kswz;

    const int am = rb * 64 + (lane & 15);
    const int bn = cb * 64 + (lane & 15);
    const int ko = (((lane >> 4) ^ ((lane >> 1) & 3)) * 8);

    // prologue: issue step-0 loads
#pragma unroll
    for (int it = 0; it < 2; ++it) {
        const size_t go = (size_t)it * 16 * 512;
        const int ld = (w * 2 + it) * 512;
        gload16(gAh + go, As_hi + ld);
        gload16(gAl + go, As_lo + ld);
        gload16(gBh + go, Bs_hi + ld);
        gload16(gBl + go, Bs_lo + ld);
    }
    gAh += BK; gAl += BK; gBh += BK; gBl += BK;

    for (int ks = 0; ks < 16; ++ks) {
        __syncthreads();   // B1: loads for this step complete (vmcnt drain)

        bf16x8 ah[4], al[4], bh[4], bl[4];
#pragma unroll
        for (int t = 0; t < 4; ++t) {
            ah[t] = ldsfrag(&As_hi[(am + t * 16) * BK + ko]);
            al[t] = ldsfrag(&As_lo[(am + t * 16) * BK + ko]);
            bh[t] = ldsfrag(&Bs_hi[(bn + t * 16) * BK + ko]);
            bl[t] = ldsfrag(&Bs_lo[(bn + t * 16) * BK + ko]);
        }
        __syncthreads();   // B2: all waves done reading; buffers free

        if (ks < 15) {     // issue next step's loads -> overlap with MFMA burst
#pragma unroll
            for (int it = 0; it < 2; ++it) {
                const size_t go = (size_t)it * 16 * 512;
                const int ld = (w * 2 + it) * 512;
                gload16(gAh + go, As_hi + ld);
                gload16(gAl + go, As_lo + ld);
                gload16(gBh + go, Bs_hi + ld);
                gload16(gBl + go, Bs_lo + ld);
            }
            gAh += BK; gAl += BK; gBh += BK; gBl += BK;
        }

#pragma unroll
        for (int i = 0; i < 4; ++i)
#pragma unroll
            for (int j = 0; j < 4; ++j) {
                acc[i][j] = __builtin_amdgcn_mfma_f32_16x16x32_bf16(al[i], bh[j], acc[i][j], 0, 0, 0);
                acc[i][j] = __builtin_amdgcn_mfma_f32_16x16x32_bf16(ah[i], bl[j], acc[i][j], 0, 0, 0);
                acc[i][j] = __builtin_amdgcn_mfma_f32_16x16x32_bf16(ah[i], bh[j], acc[i][j], 0, 0, 0);
            }
    }

    // epilogue: +bias, tanh, product over n
    const int quad = lane >> 4;
    const int c16  = lane & 15;
#pragma unroll
    for (int tj = 0; tj < 4; ++tj) {
        const int c = cb * 64 + tj * 16 + c16;
        const float bias = Wbias[r0 + c];
        float p = 1.f;
#pragma unroll
        for (int ti = 0; ti < 4; ++ti)
#pragma unroll
            for (int ri = 0; ri < 4; ++ri)
                p *= fast_tanh(acc[ti][tj][ri] + bias);
        p *= __shfl_xor(p, 16, 64);
        p *= __shfl_xor(p, 32, 64);
        if (quad == 0) red[rb][c] = p;
    }
    __syncthreads();
    if (tid < 128)
        prod_out[(size_t)b * R + r0 + tid] = red[0][tid] * red[1][tid];
}

// ---------------------------------------------------------------------------
// aggregate via MFMA: h_out = (C+I) @ h, on bf16 hi/lo pairs.
// A = C' (bf16, exact) [n][s]; B = h [s][d] staged transposed [d][s] in LDS.
// Block: (b, d-tile 128). Output 128n x 128d; 4 waves, 64x64 each; K=128, BK=32.
// ---------------------------------------------------------------------------
__global__ __launch_bounds__(256)
void aggregate_mfma_kernel(const u16* __restrict__ hi_in, const u16* __restrict__ lo_in,
                           const u16* __restrict__ Cbf,    // [B][128][128] bf16 (C+I)
                           u16* __restrict__ hi_out, u16* __restrict__ lo_out)
{
    __shared__ u16 Cs[128 * 32];          // swizzled chunks, 8 KB
    __shared__ u16 Bs_hi[128 * 40];       // [d][s], stride 40 (80B rows, 16B-aligned)
    __shared__ u16 Bs_lo[128 * 40];

    const int flat = blockIdx.x;
    const int rest = flat >> 3;
    const int b    = (flat & 7) * 32 + (rest >> 2);
    const int d0   = (rest & 3) * 128;

    const int tid  = threadIdx.x;
    const int w    = tid >> 6;
    const int lane = tid & 63;
    const int rb   = w & 1;
    const int cb   = w >> 1;

    floatx4 acc[4][4];
#pragma unroll
    for (int i = 0; i < 4; ++i)
#pragma unroll
        for (int j = 0; j < 4; ++j)
#pragma unroll
            for (int k = 0; k < 4; ++k) acc[i][j][k] = 0.f;

    // Cs staging via global_load_lds (xor-chunk swizzle; rows are 64B)
    const int kswz = (((lane & 3) ^ ((lane >> 3) & 3)) * 8);
    const u16* gC = Cbf + ((size_t)b * 128 + (w * 32 + (lane >> 2))) * 128 + kswz;

    // Bs transpose staging mapping
    const int ssi = tid >> 3;           // 0..31 (s within chunk)
    const int dg  = (tid & 7) * 16;     // 0..112
    const u16* gBh = hi_in + ((size_t)b * 128 + ssi) * 512 + d0 + dg;
    const u16* gBl = lo_in + ((size_t)b * 128 + ssi) * 512 + d0 + dg;

    const int am  = rb * 64 + (lane & 15);
    const int ko  = (((lane >> 4) ^ ((lane >> 1) & 3)) * 8);
    const int bko = (lane >> 4) * 8;

    for (int s0 = 0; s0 < 128; s0 += 32) {
        // stage Cs (async DMA)
#pragma unroll
        for (int it = 0; it < 2; ++it)
            gload16(gC + s0 + (size_t)it * 16 * 128, Cs + (w * 2 + it) * 512);

        // stage Bs transposed (vector read, scalar ds_write)
        {
            const u16* ph = gBh + (size_t)s0 * 512;
            const u16* pl = gBl + (size_t)s0 * 512;
            uint4 a0 = *(const uint4*)ph;
            uint4 a1 = *(const uint4*)(ph + 8);
            uint4 b0 = *(const uint4*)pl;
            uint4 b1 = *(const uint4*)(pl + 8);
            const u16* av0 = (const u16*)&a0; const u16* av1 = (const u16*)&a1;
            const u16* bv0 = (const u16*)&b0; const u16* bv1 = (const u16*)&b1;
#pragma unroll
            for (int i = 0; i < 8; ++i) {
                Bs_hi[(dg + i) * 40 + ssi]     = av0[i];
                Bs_hi[(dg + 8 + i) * 40 + ssi] = av1[i];
                Bs_lo[(dg + i) * 40 + ssi]     = bv0[i];
                Bs_lo[(dg + 8 + i) * 40 + ssi] = bv1[i];
            }
        }
        __syncthreads();

        bf16x8 af[4], bhf[4], blf[4];
#pragma unroll
        for (int t = 0; t < 4; ++t) {
            af[t]  = ldsfrag(&Cs[(am + t * 16) * 32 + ko]);
            const int d = cb * 64 + t * 16 + (lane & 15);
            bhf[t] = ldsfrag(&Bs_hi[d * 40 + bko]);
            blf[t] = ldsfrag(&Bs_lo[d * 40 + bko]);
        }
#pragma unroll
        for (int i = 0; i < 4; ++i)
#pragma unroll
            for (int j = 0; j < 4; ++j) {
                acc[i][j] = __builtin_amdgcn_mfma_f32_16x16x32_bf16(af[i], bhf[j], acc[i][j], 0, 0, 0);
                acc[i][j] = __builtin_amdgcn_mfma_f32_16x16x32_bf16(af[i], blf[j], acc[i][j], 0, 0, 0);
            }
        __syncthreads();
    }

    // epilogue: split to hi/lo and store
    const int quad = lane >> 4;
    const int c16  = lane & 15;
#pragma unroll
    for (int i = 0; i < 4; ++i)
#pragma unroll
        for (int j = 0; j < 4; ++j) {
            const int d = d0 + cb * 64 + j * 16 + c16;
#pragma unroll
            for (int ri = 0; ri < 4; ++ri) {
                const int n = rb * 64 + i * 16 + quad * 4 + ri;
                size_t o = ((size_t)b * 128 + n) * 512 + d;
                float v = acc[i][j][ri];
                u16 hv = f2bf(v);
                hi_out[o] = hv;
                lo_out[o] = f2bf(v - bf2f(hv));
            }
        }
}

// ---------------------------------------------------------------------------
__global__ __launch_bounds__(256)
void score_kernel(const float* __restrict__ prod,   // [L,B,R]
                  const float* __restrict__ lin_w,  // [L,R,O]
                  const float* __restrict__ lin_b,  // [L,O]
                  float* __restrict__ out)          // [B,O]
{
    const int b   = blockIdx.x;
    const int tid = threadIdx.x;

    float acc[O];
#pragma unroll
    for (int o = 0; o < O; ++o) acc[o] = 0.f;

    for (int l = 0; l < L; ++l) {
        const float* pl = prod + ((size_t)l * B + b) * R;
        const float* wl = lin_w + (size_t)l * R * O;
        for (int r = tid; r < R; r += 256) {
            const float p = pl[r];
#pragma unroll
            for (int o = 0; o < O; ++o)
                acc[o] = fmaf(p, wl[r * O + o], acc[o]);
        }
    }

    __shared__ float sb[256];
    for (int o = 0; o < O; ++o) {
        sb[tid] = acc[o];
        __syncthreads();
        for (int off = 128; off > 0; off >>= 1) {
            if (tid < off) sb[tid] += sb[tid + off];
            __syncthreads();
        }
        if (tid == 0) {
            float bias = 0.f;
            for (int l = 0; l < L; ++l) bias += lin_b[l * O + o];
            out[b * O + o] = sb[0] + bias;
        }
        __syncthreads();
    }
}

// ---------------------------------------------------------------------------
extern "C" void kernel_launch(void* const* d_in, const int* in_sizes, int n_in,
                              void* d_out, int out_size, void* d_ws, size_t ws_size,
                              hipStream_t stream) {
    const float* x     = (const float*)d_in[0];   // [B,N,D]
    const int*   edges = (const int*)d_in[1];     // [B,2,E]
    const float* W_cp  = (const float*)d_in[2];   // [L,513,1024]
    const float* lin_w = (const float*)d_in[3];   // [L,R,O]
    const float* lin_b = (const float*)d_in[4];   // [L,O]
    float*       out   = (float*)d_out;           // [B,O]

    char* ws = (char*)d_ws;
    const size_t C_BYTES   = (size_t)B * N * N * 4;        // 16.8 MB
    const size_t CBF_BYTES = (size_t)B * N * N * 2;        // 8.4 MB
    const size_t HH_BYTES  = (size_t)B * N * D * 2;        // 33.6 MB
    const size_t WT_BYTES  = (size_t)L * 1024 * 512 * 2;   // 5.24 MB

    float* C     = (float*)ws;                    ws += C_BYTES;
    u16*   Cbf   = (u16*)ws;                      ws += CBF_BYTES;
    u16*   hiA   = (u16*)ws;                      ws += HH_BYTES;
    u16*   loA   = (u16*)ws;                      ws += HH_BYTES;
    u16*   hiB   = (u16*)ws;                      ws += HH_BYTES;
    u16*   loB   = (u16*)ws;                      ws += HH_BYTES;
    u16*   Wt_hi = (u16*)ws;                      ws += WT_BYTES;
    u16*   Wt_lo = (u16*)ws;                      ws += WT_BYTES;
    float* prod  = (float*)ws;                    // [L,B,R] 5.24 MB

    zero_kernel<<<1024, 256, 0, stream>>>(C, (size_t)B * N * N);
    fill_adj_kernel<<<(B * E + 255) / 256, 256, 0, stream>>>(edges, C);
    diag_kernel<<<(B * N + 255) / 256, 256, 0, stream>>>(C);
    cbf_kernel<<<1024, 256, 0, stream>>>((const float4*)C, (ushort4*)Cbf,
                                         (size_t)B * N * N / 4);
    wt_split_kernel<<<dim3(16, 8, L), 256, 0, stream>>>(W_cp, Wt_hi, Wt_lo);
    split_kernel<<<2048, 256, 0, stream>>>((const float4*)x, (uint2*)hiA, (uint2*)loA,
                                           (size_t)B * N * D / 4);

    // layer 0
    cp_pool_mfma_kernel<<<2048, 256, 0, stream>>>(
        hiA, loA, Wt_hi, Wt_lo, W_cp + (size_t)512 * 1024, prod);

    const u16* phi = hiA; const u16* plo = loA;
    u16* bhi[2] = {hiB, hiA};
    u16* blo[2] = {loB, loA};
    for (int l = 1; l < L; ++l) {
        u16* nhi = bhi[(l - 1) & 1];
        u16* nlo = blo[(l - 1) & 1];
        aggregate_mfma_kernel<<<1024, 256, 0, stream>>>(phi, plo, Cbf, nhi, nlo);
        cp_pool_mfma_kernel<<<2048, 256, 0, stream>>>(
            nhi, nlo,
            Wt_hi + (size_t)l * 1024 * 512, Wt_lo + (size_t)l * 1024 * 512,
            W_cp + ((size_t)l * 513 + 512) * 1024,
            prod + (size_t)l * B * R);
        phi = nhi; plo = nlo;
    }

    score_kernel<<<B, 256, 0, stream>>>(prod, lin_w, lin_b, out);
}